// Round 3
// baseline (1481.482 us; speedup 1.0000x reference)
//
#include <hip/hip_runtime.h>
#include <hip/hip_bf16.h>

typedef __attribute__((ext_vector_type(8))) short bf16x8;
typedef __attribute__((ext_vector_type(4))) float f32x4;
typedef __attribute__((ext_vector_type(16))) float f32x16;
typedef __attribute__((ext_vector_type(2))) unsigned int u32x2;

constexpr int NB = 2048;
constexpr int NE = 30, NN = 8, NAll = 38;
constexpr int BAS = 32, KD = 64, ED = 128, HK = 45, HO = 91, LNUM = 3;

#define MFMA32(a, b, c) __builtin_amdgcn_mfma_f32_32x32x16_bf16((a), (b), (c), 0, 0, 0)

// hardware packed f32->bf16 (RNE)
__device__ __forceinline__ unsigned cvtpk(float a, float b) {
    unsigned r;
    asm("v_cvt_pk_bf16_f32 %0, %1, %2" : "=v"(r) : "v"(a), "v"(b));
    return r;
}
__device__ __forceinline__ unsigned short f2b(float v) {
    return (unsigned short)cvtpk(v, v);
}
__device__ __forceinline__ bf16x8 cvt8(f32x4 lo, f32x4 hi) {
    union { unsigned u[4]; bf16x8 v; } r;
    r.u[0] = cvtpk(lo[0], lo[1]);
    r.u[1] = cvtpk(lo[2], lo[3]);
    r.u[2] = cvtpk(hi[0], hi[1]);
    r.u[3] = cvtpk(hi[2], hi[3]);
    return r.v;
}
// softplus(x) - ln2 == max(x,0) + log(0.5 + 0.5*exp(-|x|))   (-ln2 folded)
__device__ __forceinline__ float ssp(float x) {
    float e = __expf(-fabsf(x));
    return fmaxf(x, 0.f) + __logf(fmaf(0.5f, e, 0.5f));
}
// XOR-swizzled element index; S = elems/row (pow2 multiple of 8)
__device__ __forceinline__ int swzi(int row, int col, int S) {
    int mask = (S >> 3) - 1;
    int blk = ((col >> 3) ^ row) & mask;
    return row * S + (blk << 3) + (col & 7);
}
__device__ __forceinline__ bf16x8 ldfrag(const unsigned short* p, int S, int row, int col) {
    int mask = (S >> 3) - 1;
    int blk = ((col >> 3) ^ row) & mask;
    return *(const bf16x8*)(p + row * S + (blk << 3));
}
__device__ __forceinline__ f32x4 ldf4s(const float* p, int S, int row, int col) {
    int mask = (S >> 3) - 1;
    int blk = ((col >> 3) ^ row) & mask;
    return *(const f32x4*)(p + row * S + (blk << 3) + (col & 7));
}

__global__ __launch_bounds__(256, 4) void schnet_mfma(
    const float* __restrict__ dists,
    const float* __restrict__ emb_e,
    const float* __restrict__ emb_n,
    const float* __restrict__ kw1, const float* __restrict__ kb1,
    const float* __restrict__ kw2, const float* __restrict__ kb2,
    const float* __restrict__ ew,
    const float* __restrict__ ow1, const float* __restrict__ ob1,
    const float* __restrict__ ow2, const float* __restrict__ ob2,
    float* __restrict__ out)
{
    // 26368 B LDS; xs state lives in global `out`
    __shared__ __align__(16) unsigned char smem[26368];
    float* zsb  = (float*)smem;                            // [38][64] f32 (rows 30..37 = nuc)
    float* stot = (float*)(smem + 9728);                   // [64] col sums of zsb
    unsigned short* w2t = (unsigned short*)(smem + 9984);  // [64 c][64 hpad] bf16 swz
    unsigned char* U = smem + 18176;                       // 8192 B: msgf f32[32][64] ∪ hob
    float* msgf = (float*)U;
    unsigned short* hobA = (unsigned short*)U;             // [32 i][64 h] bf16 swz
    unsigned short* hobB = (unsigned short*)(U + 4096);    // [32 i][32 h] bf16 swz

    const int b = blockIdx.x;
    const int t = threadIdx.x;
    const int l = t & 63, wv = t >> 6;
    const int li = l & 31, hi = l >> 5;
    const float* db_b = dists + (size_t)b * NE * NAll * BAS;
    float* xsg = out + (size_t)b * NE * ED;
    const int ri = (li < NE) ? li : NE - 1;                // clamp rows 30/31 (masked later)

    const f32x16 z16 = {0,0,0,0,0,0,0,0,0,0,0,0,0,0,0,0};

    for (int o = t; o < NE * ED; o += 256) xsg[o] = emb_e[o];
    for (int o = t; o < NN * KD; o += 256) zsb[NE * KD + o] = emb_n[o];
    __syncthreads();

    for (int lyr = 0; lyr < LNUM; ++lyr) {
        const float* w1g = kw1 + lyr * BAS * HK;
        const float* b1g = kb1 + lyr * HK;
        const float* w2g = kw2 + lyr * HK * KD;
        const float* b2g = kb2 + lyr * KD;
        const float* weg = ew  + lyr * ED * KD;
        const float* o1g = ow1 + lyr * KD * HO;
        const float* g1g = ob1 + lyr * HO;
        const float* o2g = ow2 + lyr * HO * ED;
        const float* g2g = ob2 + lyr * ED;

        // ---- stage W2 into LDS (B-frag layout [c][h], swizzled) ----
        for (int o = t; o < 64 * 64; o += 256) {
            int c = o & 63, h = o >> 6;                    // coalesced over c
            w2t[swzi(c, h, 64)] = f2b((h < HK) ? w2g[h * KD + c] : 0.f);
        }

        // ---- per-wave register weight fragments (global gathers, L2-hot) ----
        bf16x8 w1f[2][2], b1Af[2], oneB;
        {
            #pragma unroll
            for (int T = 0; T < 2; ++T) {
                int h = li + 32 * T;
                bool hv = (h < HK);
                #pragma unroll
                for (int s = 0; s < 2; ++s) {
                    f32x4 lo, hh;
                    #pragma unroll
                    for (int j2 = 0; j2 < 4; ++j2) {
                        int e0 = s * 16 + hi * 8 + j2;
                        lo[j2] = hv ? w1g[e0 * HK + h] : 0.f;
                        hh[j2] = hv ? w1g[(e0 + 4) * HK + h] : 0.f;
                    }
                    w1f[T][s] = cvt8(lo, hh);
                }
                float bv = hv ? b1g[h] : 0.f;
                union { unsigned u[4]; bf16x8 v; } bb;
                bb.u[0] = (hi == 0) ? cvtpk(bv, 0.f) : 0u;
                bb.u[1] = bb.u[2] = bb.u[3] = 0u;
                b1Af[T] = bb.v;
            }
            union { unsigned u[4]; bf16x8 v; } ob;
            ob.u[0] = (hi == 0) ? cvtpk(1.f, 0.f) : 0u;
            ob.u[1] = ob.u[2] = ob.u[3] = 0u;
            oneB = ob.v;
        }

        // ---- zs phase: zsb[0:30] = xs @ ew (waves 0,1; tile = wv) ----
        if (wv < 2) {
            f32x16 zacc = z16;
            #pragma unroll
            for (int s = 0; s < 8; ++s) {
                const float* xp = xsg + ri * ED + s * 16 + hi * 8;
                bf16x8 af = cvt8(*(const f32x4*)xp, *(const f32x4*)(xp + 4));
                f32x4 lo, hh;
                #pragma unroll
                for (int j2 = 0; j2 < 4; ++j2) {
                    int e0 = s * 16 + hi * 8 + j2;
                    lo[j2] = weg[e0 * KD + wv * 32 + li];
                    hh[j2] = weg[(e0 + 4) * KD + wv * 32 + li];
                }
                zacc = MFMA32(af, cvt8(lo, hh), zacc);
            }
            #pragma unroll
            for (int r = 0; r < 16; ++r) {
                int i = (r & 3) + 8 * (r >> 2) + 4 * hi;
                if (i < NE) zsb[i * 64 + wv * 32 + li] = zacc[r];  // keep nuc rows
            }
        }
        __syncthreads();                              // B1: zsb + w2t ready

        if (t < 64) {                                 // stot (used by wave 3 after B2)
            float s = 0.f;
            for (int j2 = 0; j2 < NAll; ++j2) s += zsb[j2 * 64 + t];
            stot[t] = s;
        }
        {   // zero msgf (U free since last layer's end barrier)
            f32x4 zz4 = {0, 0, 0, 0};
            *(f32x4*)(msgf + t * 8) = zz4;
            *(f32x4*)(msgf + t * 8 + 4) = zz4;
        }

        // ---- pair phase: per-wave, barrier-free, NO LDS round trip ----
        f32x16 mr0 = z16, mr1 = z16;

        auto pbody = [&](bool DIAG, int j) {
            const float* dp = db_b + (size_t)(ri * NAll + (DIAG ? ri : j)) * BAS + hi * 8;
            bf16x8 fb0 = cvt8(*(const f32x4*)dp, *(const f32x4*)(dp + 4));
            bf16x8 fb1 = cvt8(*(const f32x4*)(dp + 16), *(const f32x4*)(dp + 20));
            // GEMM1 swapped: D[col=i=li][row=h]; b1 folded via rank-1 MFMA
            f32x16 h0 = MFMA32(b1Af[0], oneB, z16);
            h0 = MFMA32(w1f[0][0], fb0, h0);
            h0 = MFMA32(w1f[0][1], fb1, h0);
            f32x16 h1 = MFMA32(b1Af[1], oneB, z16);
            h1 = MFMA32(w1f[1][0], fb0, h1);
            h1 = MFMA32(w1f[1][1], fb1, h1);
            // ssp + pack: dword d of tile T covers h = 2*(d&1)+8*(d>>1)+4*hi+32*T
            unsigned d0 = cvtpk(ssp(h0[0]),  ssp(h0[1]));
            unsigned d1 = cvtpk(ssp(h0[2]),  ssp(h0[3]));
            unsigned d2 = cvtpk(ssp(h0[4]),  ssp(h0[5]));
            unsigned d3 = cvtpk(ssp(h0[6]),  ssp(h0[7]));
            unsigned d4 = cvtpk(ssp(h0[8]),  ssp(h0[9]));
            unsigned d5 = cvtpk(ssp(h0[10]), ssp(h0[11]));
            unsigned d6 = cvtpk(ssp(h0[12]), ssp(h0[13]));
            unsigned d7 = cvtpk(ssp(h0[14]), ssp(h0[15]));
            unsigned e0 = cvtpk(ssp(h1[0]),  ssp(h1[1]));
            unsigned e1 = cvtpk(ssp(h1[2]),  ssp(h1[3]));
            unsigned e2 = cvtpk(ssp(h1[4]),  ssp(h1[5]));
            unsigned e3 = cvtpk(ssp(h1[6]),  ssp(h1[7]));
            // in-register redistribution: partner = lane ^ 32
            unsigned pd0 = __shfl_xor(d0, 32, 64), pd1 = __shfl_xor(d1, 32, 64);
            unsigned pd2 = __shfl_xor(d2, 32, 64), pd3 = __shfl_xor(d3, 32, 64);
            unsigned pd4 = __shfl_xor(d4, 32, 64), pd5 = __shfl_xor(d5, 32, 64);
            unsigned pd6 = __shfl_xor(d6, 32, 64), pd7 = __shfl_xor(d7, 32, 64);
            unsigned pe0 = __shfl_xor(e0, 32, 64), pe1 = __shfl_xor(e1, 32, 64);
            unsigned pe2 = __shfl_xor(e2, 32, 64), pe3 = __shfl_xor(e3, 32, 64);
            const bool h0s = (hi == 0);
            union { unsigned u[4]; bf16x8 v; } f0, f1, f2;
            f0.u[0] = h0s ? d0 : pd2;  f0.u[1] = h0s ? d1 : pd3;
            f0.u[2] = h0s ? pd0 : d2;  f0.u[3] = h0s ? pd1 : d3;
            f1.u[0] = h0s ? d4 : pd6;  f1.u[1] = h0s ? d5 : pd7;
            f1.u[2] = h0s ? pd4 : d6;  f1.u[3] = h0s ? pd5 : d7;
            f2.u[0] = h0s ? e0 : pe2;  f2.u[1] = h0s ? e1 : pe3;
            f2.u[2] = h0s ? pe0 : e2;  f2.u[3] = h0s ? pe1 : e3;
            // GEMM2: A=H-frags, B=w2 from LDS (read-only, late loads)
            f32x16 a2 = MFMA32(f0.v, ldfrag(w2t, 64, li, hi * 8), z16);
            a2 = MFMA32(f1.v, ldfrag(w2t, 64, li, 16 + hi * 8), a2);
            a2 = MFMA32(f2.v, ldfrag(w2t, 64, li, 32 + hi * 8), a2);
            if (DIAG) {
                #pragma unroll
                for (int r = 0; r < 16; ++r)
                    mr0[r] -= a2[r] * zsb[((r & 3) + 8 * (r >> 2) + 4 * hi) * 64 + li];
            } else {
                float zv = zsb[j * 64 + li];
                #pragma unroll
                for (int r = 0; r < 16; ++r) mr0[r] += a2[r] * zv;
            }
            a2 = MFMA32(f0.v, ldfrag(w2t, 64, 32 + li, hi * 8), z16);
            a2 = MFMA32(f1.v, ldfrag(w2t, 64, 32 + li, 16 + hi * 8), a2);
            a2 = MFMA32(f2.v, ldfrag(w2t, 64, 32 + li, 32 + hi * 8), a2);
            if (DIAG) {
                #pragma unroll
                for (int r = 0; r < 16; ++r)
                    mr1[r] -= a2[r] * zsb[((r & 3) + 8 * (r >> 2) + 4 * hi) * 64 + 32 + li];
            } else {
                float zv = zsb[j * 64 + 32 + li];
                #pragma unroll
                for (int r = 0; r < 16; ++r) mr1[r] += a2[r] * zv;
            }
        };

        for (int j = wv; j < NAll; j += 4) pbody(false, j);
        if (wv == 2) pbody(true, 0);                  // subtract W(i,i)*zs_i
        __syncthreads();                              // B2: zero-msgf visible, stot ready

        if (wv == 3) {                                // factored b2: + b2*(stot - zs_i)
            float b2a = b2g[li], b2b = b2g[32 + li];
            float sta = stot[li], stb = stot[32 + li];
            #pragma unroll
            for (int r = 0; r < 16; ++r) {
                int i = (r & 3) + 8 * (r >> 2) + 4 * hi;
                mr0[r] += b2a * (sta - zsb[i * 64 + li]);
                mr1[r] += b2b * (stb - zsb[i * 64 + 32 + li]);
            }
        }
        #pragma unroll
        for (int r = 0; r < 16; ++r) {
            int i = (r & 3) + 8 * (r >> 2) + 4 * hi;
            atomicAdd(msgf + swzi(i, li, 64), mr0[r]);
            atomicAdd(msgf + swzi(i, 32 + li, 64), mr1[r]);
        }
        __syncthreads();                              // B3: msgf complete

        // ---- out phase ----
        f32x16 oacc = z16;
        f32x4 g1q[4];
        if (wv < 3) {                                 // o1 swapped: tile T=wv (h=li+32T)
            int h = li + 32 * wv;
            bool hv = (h < HO);
            #pragma unroll
            for (int s = 0; s < 4; ++s) {
                bf16x8 bm = cvt8(ldf4s(msgf, 64, li, s * 16 + hi * 8),
                                 ldf4s(msgf, 64, li, s * 16 + hi * 8 + 4));
                f32x4 lo, hh;
                #pragma unroll
                for (int j2 = 0; j2 < 4; ++j2) {
                    int m = s * 16 + hi * 8 + j2;
                    lo[j2] = hv ? o1g[m * HO + h] : 0.f;
                    hh[j2] = hv ? o1g[(m + 4) * HO + h] : 0.f;
                }
                oacc = MFMA32(cvt8(lo, hh), bm, oacc);
            }
            #pragma unroll
            for (int g = 0; g < 4; ++g)
                #pragma unroll
                for (int j2 = 0; j2 < 4; ++j2) {
                    int h2 = 32 * wv + 8 * g + 4 * hi + j2;
                    g1q[g][j2] = (h2 < HO) ? g1g[h2] : 0.f;
                }
        }
        __syncthreads();                              // B4: msgf reads done -> hob overlay
        if (wv < 3) {
            #pragma unroll
            for (int g = 0; g < 4; ++g) {
                u32x2 hv2;
                hv2.x = cvtpk(ssp(oacc[4 * g + 0] + g1q[g][0]), ssp(oacc[4 * g + 1] + g1q[g][1]));
                hv2.y = cvtpk(ssp(oacc[4 * g + 2] + g1q[g][2]), ssp(oacc[4 * g + 3] + g1q[g][3]));
                int colA = 8 * g + 4 * hi;
                if (wv < 2) *(u32x2*)(hobA + swzi(li, 32 * wv + colA, 64)) = hv2;
                else        *(u32x2*)(hobB + swzi(li, colA, 32)) = hv2;
            }
        }
        __syncthreads();                              // B5: hob ready
        {   // o2: all waves, e-tile = wv; xs += ssp(..)@o2 + g2
            f32x16 xacc = z16;
            #pragma unroll
            for (int s = 0; s < 6; ++s) {
                bf16x8 af = (s < 4) ? ldfrag(hobA, 64, li, s * 16 + hi * 8)
                                    : ldfrag(hobB, 32, li, (s - 4) * 16 + hi * 8);
                f32x4 lo, hh;
                #pragma unroll
                for (int j2 = 0; j2 < 4; ++j2) {
                    int h2 = s * 16 + hi * 8 + j2;
                    lo[j2] = (h2 < HO) ? o2g[h2 * ED + wv * 32 + li] : 0.f;
                    hh[j2] = (h2 + 4 < HO) ? o2g[(h2 + 4) * ED + wv * 32 + li] : 0.f;
                }
                xacc = MFMA32(af, cvt8(lo, hh), xacc);
            }
            float g2v = g2g[wv * 32 + li];
            #pragma unroll
            for (int r = 0; r < 16; ++r) {
                int i = (r & 3) + 8 * (r >> 2) + 4 * hi;
                if (i < NE) xsg[i * ED + wv * 32 + li] += xacc[r] + g2v;
            }
        }
        __syncthreads();                              // B6: layer end (xsg/U reuse safe)
    }
    // xs accumulated directly in `out`
}

extern "C" void kernel_launch(void* const* d_in, const int* in_sizes, int n_in,
                              void* d_out, int out_size, void* d_ws, size_t ws_size,
                              hipStream_t stream) {
    const float* dists = (const float*)d_in[0];
    const float* emb_e = (const float*)d_in[1];
    const float* emb_n = (const float*)d_in[2];
    const float* kw1   = (const float*)d_in[3];
    const float* kb1   = (const float*)d_in[4];
    const float* kw2   = (const float*)d_in[5];
    const float* kb2   = (const float*)d_in[6];
    const float* ew    = (const float*)d_in[7];
    const float* ow1   = (const float*)d_in[8];
    const float* ob1   = (const float*)d_in[9];
    const float* ow2   = (const float*)d_in[10];
    const float* ob2   = (const float*)d_in[11];
    float* out = (float*)d_out;

    schnet_mfma<<<NB, 256, 0, stream>>>(dists, emb_e, emb_n, kw1, kb1, kw2, kb2,
                                        ew, ow1, ob1, ow2, ob2, out);
}